// Round 1
// baseline (353.144 us; speedup 1.0000x reference)
//
#include <hip/hip_runtime.h>
#include <hip/hip_bf16.h>
#include <stdint.h>

typedef __bf16 bf16_t;
typedef __bf16 bf16x4 __attribute__((ext_vector_type(4)));
typedef __bf16 bf16x8 __attribute__((ext_vector_type(8)));
typedef float f32x4 __attribute__((ext_vector_type(4)));

#define BM 128
#define BN 128
#define BK 32

// Async global->LDS, 16B per lane. LDS dst is wave-uniform base + lane*16.
__device__ __forceinline__ void async_ld16(const bf16_t* g, bf16_t* lds) {
    __builtin_amdgcn_global_load_lds(
        (__attribute__((address_space(1))) void*)g,
        (__attribute__((address_space(3))) void*)lds,
        16, 0, 0);
}

// ---------------- conversion kernels ----------------

__global__ void cvt4_f32_bf16(const float* __restrict__ in, bf16_t* __restrict__ out, int n4) {
    int i = blockIdx.x * 256 + threadIdx.x;
    if (i >= n4) return;
    float4 v = ((const float4*)in)[i];
    bf16x4 o = { (bf16_t)v.x, (bf16_t)v.y, (bf16_t)v.z, (bf16_t)v.w };
    ((bf16x4*)out)[i] = o;
}

// in: [R][C] fp32 row-major -> out: [Cp][R] bf16 row-major (transpose + convert),
// rows C..Cp-1 of out zero-filled.
__global__ void transpose_cvt(const float* __restrict__ in, bf16_t* __restrict__ out,
                              int R, int C, int Cp) {
    __shared__ float tile[32][33];
    const int c0 = blockIdx.x * 32;   // output-row block (original column)
    const int r0 = blockIdx.y * 32;   // original row block
    const int tx = threadIdx.x;       // 0..31
    const int ty = threadIdx.y;       // 0..7
#pragma unroll
    for (int i = 0; i < 32; i += 8) {
        int rr = r0 + ty + i, cc = c0 + tx;
        float v = 0.f;
        if (rr < R && cc < C) v = in[(size_t)rr * C + cc];
        tile[ty + i][tx] = v;
    }
    __syncthreads();
#pragma unroll
    for (int i = 0; i < 32; i += 8) {
        int oc = c0 + ty + i;   // output row
        int orr = r0 + tx;      // output col
        if (oc < Cp && orr < R)
            out[(size_t)oc * R + orr] = (bf16_t)tile[tx][ty + i];
    }
}

// ---------------- GEMM: C_partial[s] = A_chunk . B_chunk^T ----------------
// A: [M][K] bf16 row-major. B: [N][K] bf16 row-major (i.e. weights transposed).
// P: [S][M][N] fp32 partials. Grid: (M/128, N/128, S).
__global__ __launch_bounds__(256) void gemm_bf16(
    const bf16_t* __restrict__ A, const bf16_t* __restrict__ B,
    float* __restrict__ P, int M, int N, int K, int Kchunk)
{
    __shared__ __align__(16) bf16_t Asm[BM * BK];
    __shared__ __align__(16) bf16_t Bsm[BN * BK];

    const int tid  = threadIdx.x;
    const int wave = tid >> 6;
    const int lane = tid & 63;
    const int bm = blockIdx.x, bn = blockIdx.y, s = blockIdx.z;

    const bf16_t* Ab = A + (size_t)bm * BM * K + (size_t)s * Kchunk;
    const bf16_t* Bb = B + (size_t)bn * BN * K + (size_t)s * Kchunk;

    // staging coordinates: each lane moves 16B (8 bf16): row = lane/4, koff = (lane%4)*8
    const int ar = lane >> 2;
    const int ak = (lane & 3) * 8;

    // wave quadrant (64x64) within 128x128 tile
    const int wm = (wave >> 1) * 64;
    const int wn = (wave & 1) * 64;
    const int kq = (lane >> 4) * 8;   // which k-octet this lane reads
    const int r  = lane & 15;         // m (A) / n (B) index within 16-tile

    f32x4 acc[4][4];
#pragma unroll
    for (int i = 0; i < 4; ++i)
#pragma unroll
        for (int j = 0; j < 4; ++j)
            acc[i][j] = f32x4{0.f, 0.f, 0.f, 0.f};

    for (int k0 = 0; k0 < Kchunk; k0 += BK) {
        __syncthreads();   // previous iter's ds_reads complete before overwrite
#pragma unroll
        for (int i = 0; i < 2; ++i) {
            const int rb = (wave * 2 + i) * 16;   // 16 rows per wave-issue
            async_ld16(Ab + (size_t)(rb + ar) * K + (k0 + ak), &Asm[rb * BK]);
            async_ld16(Bb + (size_t)(rb + ar) * K + (k0 + ak), &Bsm[rb * BK]);
        }
        __syncthreads();   // compiler emits s_waitcnt vmcnt(0) before s_barrier

        bf16x8 af[4], bfr[4];
#pragma unroll
        for (int i = 0; i < 4; ++i)
            af[i] = *(const bf16x8*)&Asm[(wm + i * 16 + r) * BK + kq];
#pragma unroll
        for (int j = 0; j < 4; ++j)
            bfr[j] = *(const bf16x8*)&Bsm[(wn + j * 16 + r) * BK + kq];
#pragma unroll
        for (int i = 0; i < 4; ++i)
#pragma unroll
            for (int j = 0; j < 4; ++j)
                acc[i][j] = __builtin_amdgcn_mfma_f32_16x16x32_bf16(af[i], bfr[j], acc[i][j], 0, 0, 0);
    }

    // epilogue: C/D layout col=lane&15, row=(lane>>4)*4+reg
    float* Pb = P + ((size_t)s * M + (size_t)bm * BM) * N + (size_t)bn * BN;
    const int r4 = (lane >> 4) * 4;
    const int c  = lane & 15;
#pragma unroll
    for (int i = 0; i < 4; ++i)
#pragma unroll
        for (int j = 0; j < 4; ++j)
#pragma unroll
            for (int rg = 0; rg < 4; ++rg)
                Pb[(size_t)(wm + i * 16 + r4 + rg) * N + (wn + j * 16 + c)] = acc[i][j][rg];
}

// ---------------- reductions / epilogues ----------------

// h[i] = bf16(relu(sum_s P[s][i] + bias[i & Nm1])), vectorized x4
__global__ void reduce_relu_bf16_k(const float* __restrict__ P, const float* __restrict__ bias,
                                   bf16_t* __restrict__ h, int S, int MN, int Nm1) {
    int i4 = (blockIdx.x * 256 + threadIdx.x) * 4;
    if (i4 >= MN) return;
    int n = i4 & Nm1;
    float4 a = *(const float4*)(bias + n);
    for (int s = 0; s < S; ++s) {
        float4 p = *(const float4*)(P + (size_t)s * MN + i4);
        a.x += p.x; a.y += p.y; a.z += p.z; a.w += p.w;
    }
    a.x = fmaxf(a.x, 0.f); a.y = fmaxf(a.y, 0.f);
    a.z = fmaxf(a.z, 0.f); a.w = fmaxf(a.w, 0.f);
    bf16x4 o = { (bf16_t)a.x, (bf16_t)a.y, (bf16_t)a.z, (bf16_t)a.w };
    *(bf16x4*)(h + i4) = o;
}

// out[m][n] = P[m][n (of NCP)] + bc[n], n < NC
__global__ void reduce_out_k(const float* __restrict__ P, const float* __restrict__ bc,
                             float* __restrict__ out, int M, int NC, int NCP) {
    int idx = blockIdx.x * 256 + threadIdx.x;
    if (idx >= M * NC) return;
    int m = idx / NC;
    int n = idx - m * NC;
    out[idx] = P[(size_t)m * NCP + n] + bc[n];
}

// ---------------- launcher ----------------

extern "C" void kernel_launch(void* const* d_in, const int* in_sizes, int n_in,
                              void* d_out, int out_size, void* d_ws, size_t ws_size,
                              hipStream_t stream) {
    const float* X  = (const float*)d_in[0];
    // d_in[1] = batch_indices: group->MLP->ungroup is an identity permutation; unused.
    const float* W1 = (const float*)d_in[2];
    const float* b1 = (const float*)d_in[3];
    const float* W2 = (const float*)d_in[4];
    const float* b2 = (const float*)d_in[5];
    const float* Wc = (const float*)d_in[6];
    const float* bc = (const float*)d_in[7];
    float* out = (float*)d_out;

    const int M    = in_sizes[1];            // 2048
    const int FEAT = in_sizes[0] / M;        // 12544
    const int HID  = in_sizes[3];            // 1024
    const int NC   = in_sizes[7];            // 81
    const int NCP  = 128;                    // padded class dim for MFMA

    char* ws = (char*)d_ws;
    size_t off = 0;
    auto alloc = [&](size_t bytes) {
        char* p = ws + off;
        off += (bytes + 255) & ~(size_t)255;
        return p;
    };
    bf16_t* Xb  = (bf16_t*)alloc((size_t)M * FEAT * 2);
    bf16_t* W1T = (bf16_t*)alloc((size_t)FEAT * HID * 2);
    bf16_t* W2T = (bf16_t*)alloc((size_t)HID * HID * 2);
    bf16_t* WcT = (bf16_t*)alloc((size_t)NCP * HID * 2);
    bf16_t* h1  = (bf16_t*)alloc((size_t)M * HID * 2);
    bf16_t* h2  = (bf16_t*)alloc((size_t)M * HID * 2);
    float*  P   = (float*)(ws + off);

    size_t rem  = ws_size > off ? ws_size - off : 0;
    size_t perS = (size_t)M * HID * 4;
    int S1 = (rem >= 4 * perS) ? 4 : (rem >= 2 * perS ? 2 : 1);  // FEAT/S1 stays %32==0
    int S2 = (S1 >= 2) ? 2 : 1;

    // 1) convert inputs to bf16 (weights transposed to [N][K])
    int n4 = (M * FEAT) / 4;
    cvt4_f32_bf16<<<(n4 + 255) / 256, 256, 0, stream>>>(X, Xb, n4);
    dim3 tt(32, 8);
    transpose_cvt<<<dim3(HID / 32, FEAT / 32), tt, 0, stream>>>(W1, W1T, FEAT, HID, HID);
    transpose_cvt<<<dim3(HID / 32, HID / 32), tt, 0, stream>>>(W2, W2T, HID, HID, HID);
    transpose_cvt<<<dim3(NCP / 32, HID / 32), tt, 0, stream>>>(Wc, WcT, HID, NC, NCP);

    // 2) layer 1: h1 = relu(X@W1 + b1), split-K
    gemm_bf16<<<dim3(M / BM, HID / BN, S1), 256, 0, stream>>>(Xb, W1T, P, M, HID, FEAT, FEAT / S1);
    reduce_relu_bf16_k<<<(M * HID / 4 + 255) / 256, 256, 0, stream>>>(P, b1, h1, S1, M * HID, HID - 1);

    // 3) layer 2: h2 = relu(h1@W2 + b2), split-K
    gemm_bf16<<<dim3(M / BM, HID / BN, S2), 256, 0, stream>>>(h1, W2T, P, M, HID, HID, HID / S2);
    reduce_relu_bf16_k<<<(M * HID / 4 + 255) / 256, 256, 0, stream>>>(P, b2, h2, S2, M * HID, HID - 1);

    // 4) classifier: logits = h2@Wc + bc (N padded to 128)
    gemm_bf16<<<dim3(M / BM, NCP / BN, 1), 256, 0, stream>>>(h2, WcT, P, M, NCP, HID, HID);
    reduce_out_k<<<(M * NC + 255) / 256, 256, 0, stream>>>(P, bc, out, M, NC, NCP);
}

// Round 2
// 323.839 us; speedup vs baseline: 1.0905x; 1.0905x over previous
//
#include <hip/hip_runtime.h>
#include <hip/hip_bf16.h>
#include <stdint.h>

typedef __bf16 bf16_t;
typedef __bf16 bf16x4 __attribute__((ext_vector_type(4)));
typedef __bf16 bf16x8 __attribute__((ext_vector_type(8)));
typedef float f32x4 __attribute__((ext_vector_type(4)));

#define BM 128
#define BN 128
#define BK 32

// Async global->LDS, 16B per lane. LDS dst is wave-uniform base + lane*16.
__device__ __forceinline__ void async_ld16(const bf16_t* g, bf16_t* lds) {
    __builtin_amdgcn_global_load_lds(
        (__attribute__((address_space(1))) void*)g,
        (__attribute__((address_space(3))) void*)lds,
        16, 0, 0);
}

// ---------------- fused prep: X convert + 3 weight transposes ----------------

// Transpose+convert one 32x32 tile: in [R][C] fp32 -> out [Cp][R] bf16,
// rows C..Cp-1 of out zero-filled.
__device__ __forceinline__ void transpose_tile(
    const float* __restrict__ in, bf16_t* __restrict__ out,
    int R, int C, int Cp, int tileIdx, int tid, float (*tile)[33])
{
    const int tilesX = Cp / 32;
    const int c0 = (tileIdx % tilesX) * 32;
    const int r0 = (tileIdx / tilesX) * 32;
    const int tx = tid & 31;
    const int ty = tid >> 5;   // 0..7
#pragma unroll
    for (int i = 0; i < 32; i += 8) {
        int rr = r0 + ty + i, cc = c0 + tx;
        float v = 0.f;
        if (cc < C) v = in[(size_t)rr * C + cc];   // R tiles always in-bounds
        tile[ty + i][tx] = v;
    }
    __syncthreads();
#pragma unroll
    for (int i = 0; i < 32; i += 8) {
        int oc = c0 + ty + i;   // output row (original column, padded)
        int orr = r0 + tx;      // output col (original row)
        out[(size_t)oc * R + orr] = (bf16_t)tile[tx][ty + i];
    }
}

__global__ void prep_all(const float* __restrict__ X, bf16_t* __restrict__ Xb, int n4,
                         const float* __restrict__ W1, bf16_t* __restrict__ W1T,
                         const float* __restrict__ W2, bf16_t* __restrict__ W2T,
                         const float* __restrict__ Wc, bf16_t* __restrict__ WcT,
                         int FEAT, int HID, int NC, int NCP,
                         int nCvt, int t1, int t2)
{
    __shared__ float tile[32][33];
    int bid = blockIdx.x;
    int tid = threadIdx.x;
    if (bid < nCvt) {
        int i = bid * 256 + tid;
        if (i < n4) {
            float4 v = ((const float4*)X)[i];
            bf16x4 o = { (bf16_t)v.x, (bf16_t)v.y, (bf16_t)v.z, (bf16_t)v.w };
            ((bf16x4*)Xb)[i] = o;
        }
        return;
    }
    bid -= nCvt;
    if (bid < t1) { transpose_tile(W1, W1T, FEAT, HID, HID, bid, tid, tile); return; }
    bid -= t1;
    if (bid < t2) { transpose_tile(W2, W2T, HID, HID, HID, bid, tid, tile); return; }
    bid -= t2;
    transpose_tile(Wc, WcT, HID, NC, NCP, bid, tid, tile);
}

// ---------------- GEMM: P[s] = A_chunk . B_chunk^T ----------------
// A: [M][K] bf16 row-major. B: [N][K] bf16 row-major (weights transposed).
// P: [S][M][N] fp32 partials. Grid: (M/128, N/128, S).
__global__ __launch_bounds__(256) void gemm_bf16(
    const bf16_t* __restrict__ A, const bf16_t* __restrict__ B,
    float* __restrict__ P, int M, int N, int K, int Kchunk)
{
    __shared__ __align__(16) bf16_t Asm[BM * BK];
    __shared__ __align__(16) bf16_t Bsm[BN * BK];

    const int tid  = threadIdx.x;
    const int wave = tid >> 6;
    const int lane = tid & 63;
    const int bm = blockIdx.x, bn = blockIdx.y, s = blockIdx.z;

    const bf16_t* Ab = A + (size_t)bm * BM * K + (size_t)s * Kchunk;
    const bf16_t* Bb = B + (size_t)bn * BN * K + (size_t)s * Kchunk;

    // staging: each lane moves 16B (8 bf16): row = lane/4, koff = (lane%4)*8
    const int ar = lane >> 2;
    const int ak = (lane & 3) * 8;

    // wave quadrant (64x64) within 128x128 tile
    const int wm = (wave >> 1) * 64;
    const int wn = (wave & 1) * 64;
    const int kq = (lane >> 4) * 8;
    const int r  = lane & 15;

    f32x4 acc[4][4];
#pragma unroll
    for (int i = 0; i < 4; ++i)
#pragma unroll
        for (int j = 0; j < 4; ++j)
            acc[i][j] = f32x4{0.f, 0.f, 0.f, 0.f};

    for (int k0 = 0; k0 < Kchunk; k0 += BK) {
        __syncthreads();
#pragma unroll
        for (int i = 0; i < 2; ++i) {
            const int rb = (wave * 2 + i) * 16;
            async_ld16(Ab + (size_t)(rb + ar) * K + (k0 + ak), &Asm[rb * BK]);
            async_ld16(Bb + (size_t)(rb + ar) * K + (k0 + ak), &Bsm[rb * BK]);
        }
        __syncthreads();

        bf16x8 af[4], bfr[4];
#pragma unroll
        for (int i = 0; i < 4; ++i)
            af[i] = *(const bf16x8*)&Asm[(wm + i * 16 + r) * BK + kq];
#pragma unroll
        for (int j = 0; j < 4; ++j)
            bfr[j] = *(const bf16x8*)&Bsm[(wn + j * 16 + r) * BK + kq];
#pragma unroll
        for (int i = 0; i < 4; ++i)
#pragma unroll
            for (int j = 0; j < 4; ++j)
                acc[i][j] = __builtin_amdgcn_mfma_f32_16x16x32_bf16(af[i], bfr[j], acc[i][j], 0, 0, 0);
    }

    // epilogue: C/D layout col=lane&15, row=(lane>>4)*4+reg
    float* Pb = P + ((size_t)s * M + (size_t)bm * BM) * N + (size_t)bn * BN;
    const int r4 = (lane >> 4) * 4;
    const int c  = lane & 15;
#pragma unroll
    for (int i = 0; i < 4; ++i)
#pragma unroll
        for (int j = 0; j < 4; ++j)
#pragma unroll
            for (int rg = 0; rg < 4; ++rg)
                Pb[(size_t)(wm + i * 16 + r4 + rg) * N + (wn + j * 16 + c)] = acc[i][j][rg];
}

// ---------------- reductions / epilogues ----------------

// h[i] = bf16(relu(sum_s P[s][i] + bias[i & Nm1])), vectorized x4
template <int S>
__global__ void reduce_relu_bf16_k(const float* __restrict__ P, const float* __restrict__ bias,
                                   bf16_t* __restrict__ h, int MN, int Nm1) {
    int i4 = (blockIdx.x * 256 + threadIdx.x) * 4;
    if (i4 >= MN) return;
    int n = i4 & Nm1;
    float4 a = *(const float4*)(bias + n);
#pragma unroll
    for (int s = 0; s < S; ++s) {
        float4 p = *(const float4*)(P + (size_t)s * MN + i4);
        a.x += p.x; a.y += p.y; a.z += p.z; a.w += p.w;
    }
    a.x = fmaxf(a.x, 0.f); a.y = fmaxf(a.y, 0.f);
    a.z = fmaxf(a.z, 0.f); a.w = fmaxf(a.w, 0.f);
    bf16x4 o = { (bf16_t)a.x, (bf16_t)a.y, (bf16_t)a.z, (bf16_t)a.w };
    *(bf16x4*)(h + i4) = o;
}

// out[m][n] = sum_s P[s][m][n (of NCP)] + bc[n], n < NC
template <int S>
__global__ void reduce_out_k(const float* __restrict__ P, const float* __restrict__ bc,
                             float* __restrict__ out, int M, int NC, int NCP) {
    int idx = blockIdx.x * 256 + threadIdx.x;
    if (idx >= M * NC) return;
    int m = idx / NC;
    int n = idx - m * NC;
    float a = bc[n];
    size_t MN = (size_t)M * NCP;
#pragma unroll
    for (int s = 0; s < S; ++s)
        a += P[s * MN + (size_t)m * NCP + n];
    out[idx] = a;
}

// ---------------- launcher ----------------

extern "C" void kernel_launch(void* const* d_in, const int* in_sizes, int n_in,
                              void* d_out, int out_size, void* d_ws, size_t ws_size,
                              hipStream_t stream) {
    const float* X  = (const float*)d_in[0];
    // d_in[1] = batch_indices: group->MLP->ungroup is an identity permutation; unused.
    const float* W1 = (const float*)d_in[2];
    const float* b1 = (const float*)d_in[3];
    const float* W2 = (const float*)d_in[4];
    const float* b2 = (const float*)d_in[5];
    const float* Wc = (const float*)d_in[6];
    const float* bc = (const float*)d_in[7];
    float* out = (float*)d_out;

    const int M    = in_sizes[1];            // 2048
    const int FEAT = in_sizes[0] / M;        // 12544
    const int HID  = in_sizes[3];            // 1024
    const int NC   = in_sizes[7];            // 81
    const int NCP  = 128;                    // padded class dim for MFMA

    char* ws = (char*)d_ws;
    size_t off = 0;
    auto alloc = [&](size_t bytes) {
        char* p = ws + off;
        off += (bytes + 255) & ~(size_t)255;
        return p;
    };
    bf16_t* Xb  = (bf16_t*)alloc((size_t)M * FEAT * 2);
    bf16_t* W1T = (bf16_t*)alloc((size_t)FEAT * HID * 2);
    bf16_t* W2T = (bf16_t*)alloc((size_t)HID * HID * 2);
    bf16_t* WcT = (bf16_t*)alloc((size_t)NCP * HID * 2);
    bf16_t* h1  = (bf16_t*)alloc((size_t)M * HID * 2);
    bf16_t* h2  = (bf16_t*)alloc((size_t)M * HID * 2);
    float*  P   = (float*)(ws + off);

    size_t rem  = ws_size > off ? ws_size - off : 0;
    size_t perS = (size_t)M * HID * 4;
    // FEAT=12544: FEAT/S % 32 == 0 for S in {1,2,4,8}
    int S1 = (rem >= 8 * perS) ? 8 : (rem >= 4 * perS) ? 4 : (rem >= 2 * perS) ? 2 : 1;
    int S2 = (S1 >= 4) ? 4 : S1;
    // GEMM3 partials: S3*M*NCP <= S1_min_capacity (M*HID = 8*M*NCP), so S3=8 always fits.
    const int S3 = 8;

    // 1) one fused prep kernel: X->bf16, W1/W2/Wc -> transposed bf16 [N][K]
    int n4   = (M * FEAT) / 4;
    int nCvt = (n4 + 255) / 256;
    int t1 = (HID / 32) * (FEAT / 32);
    int t2 = (HID / 32) * (HID / 32);
    int t3 = (NCP / 32) * (HID / 32);
    prep_all<<<nCvt + t1 + t2 + t3, 256, 0, stream>>>(
        X, Xb, n4, W1, W1T, W2, W2T, Wc, WcT, FEAT, HID, NC, NCP, nCvt, t1, t2);

    // 2) layer 1: h1 = relu(X@W1 + b1), split-K
    gemm_bf16<<<dim3(M / BM, HID / BN, S1), 256, 0, stream>>>(Xb, W1T, P, M, HID, FEAT, FEAT / S1);
    switch (S1) {
        case 8: reduce_relu_bf16_k<8><<<(M * HID / 4 + 255) / 256, 256, 0, stream>>>(P, b1, h1, M * HID, HID - 1); break;
        case 4: reduce_relu_bf16_k<4><<<(M * HID / 4 + 255) / 256, 256, 0, stream>>>(P, b1, h1, M * HID, HID - 1); break;
        case 2: reduce_relu_bf16_k<2><<<(M * HID / 4 + 255) / 256, 256, 0, stream>>>(P, b1, h1, M * HID, HID - 1); break;
        default: reduce_relu_bf16_k<1><<<(M * HID / 4 + 255) / 256, 256, 0, stream>>>(P, b1, h1, M * HID, HID - 1); break;
    }

    // 3) layer 2: h2 = relu(h1@W2 + b2), split-K
    gemm_bf16<<<dim3(M / BM, HID / BN, S2), 256, 0, stream>>>(h1, W2T, P, M, HID, HID, HID / S2);
    switch (S2) {
        case 4: reduce_relu_bf16_k<4><<<(M * HID / 4 + 255) / 256, 256, 0, stream>>>(P, b2, h2, M * HID, HID - 1); break;
        case 2: reduce_relu_bf16_k<2><<<(M * HID / 4 + 255) / 256, 256, 0, stream>>>(P, b2, h2, M * HID, HID - 1); break;
        default: reduce_relu_bf16_k<1><<<(M * HID / 4 + 255) / 256, 256, 0, stream>>>(P, b2, h2, M * HID, HID - 1); break;
    }

    // 4) classifier: logits = h2@Wc + bc (N padded to 128), split-K
    gemm_bf16<<<dim3(M / BM, NCP / BN, S3), 256, 0, stream>>>(h2, WcT, P, M, NCP, HID, HID / S3);
    reduce_out_k<S3><<<(M * NC + 255) / 256, 256, 0, stream>>>(P, bc, out, M, NC, NCP);
}